// Round 1
// baseline (537.534 us; speedup 1.0000x reference)
//
#include <hip/hip_runtime.h>
#include <hip/hip_bf16.h>

#define SROWS 16384
#define DIMK  4096
#define NE    64
#define RPW   8            // rows per wave
#define NWAVE 4
#define BR    (RPW*NWAVE)  // 32 rows per block
#define NBLK  (SROWS/BR)   // 512 blocks
#define DC    128          // D-chunk staged in LDS
#define WSTR  132          // padded row stride (132/4=33 odd -> conflict-free b128)
#define NCH   (DIMK/DC)    // 32

__global__ __launch_bounds__(256, 2) void gate_main(
    const float* __restrict__ x, const float* __restrict__ W,
    const float* __restrict__ b, float* __restrict__ out, float* __restrict__ ws)
{
    __shared__ float Wl[NE * WSTR];   // 64*132*4 = 33792 B
    const int tid  = threadIdx.x;
    const int lane = tid & 63;
    const int wid  = __builtin_amdgcn_readfirstlane(tid >> 6);
    const int blk  = blockIdx.x;
    const int row0 = blk * BR + wid * RPW;

    float4 acc[RPW];
    #pragma unroll
    for (int r = 0; r < RPW; ++r) acc[r] = make_float4(0.f, 0.f, 0.f, 0.f);

    const float blane = b[lane];

    for (int ch = 0; ch < NCH; ++ch) {
        __syncthreads();
        // stage W[:, ch*128 .. +127] into LDS: 64x32 float4s, 256 threads -> 8 iters
        #pragma unroll
        for (int i = 0; i < (NE * DC / 4) / 256; ++i) {
            int idx = i * 256 + tid;
            int e = idx >> 5;          // 32 float4 per row
            int c = idx & 31;
            float4 v = *reinterpret_cast<const float4*>(&W[(size_t)e * DIMK + ch * DC + c * 4]);
            *reinterpret_cast<float4*>(&Wl[e * WSTR + c * 4]) = v;
        }
        __syncthreads();

        const float* xb = x + (size_t)row0 * DIMK + ch * DC;
        for (int d4 = 0; d4 < DC / 4; ++d4) {
            float4 w4 = *reinterpret_cast<const float4*>(&Wl[lane * WSTR + d4 * 4]);
            #pragma unroll
            for (int r = 0; r < RPW; ++r) {
                float4 xv = *reinterpret_cast<const float4*>(&xb[(size_t)r * DIMK + d4 * 4]);
                acc[r].x = fmaf(xv.x, w4.x, acc[r].x);
                acc[r].y = fmaf(xv.y, w4.y, acc[r].y);
                acc[r].z = fmaf(xv.z, w4.z, acc[r].z);
                acc[r].w = fmaf(xv.w, w4.w, acc[r].w);
            }
        }
    }

    // ---- epilogue: softmax + top-2 + partial reductions, all cross-lane ----
    float impAcc = 0.f;
    float cntAcc = 0.f;
    float* outIdx = out;
    float* outVal = out + (size_t)SROWS * 2;

    #pragma unroll 1
    for (int r = 0; r < RPW; ++r) {
        float logit = (acc[r].x + acc[r].y) + (acc[r].z + acc[r].w) + blane;

        // argmax with lowest-index tie-break (matches jax.lax.top_k)
        float v1 = logit; int i1 = lane;
        #pragma unroll
        for (int off = 32; off; off >>= 1) {
            float ov = __shfl_xor(v1, off);
            int   oi = __shfl_xor(i1, off);
            if (ov > v1 || (ov == v1 && oi < i1)) { v1 = ov; i1 = oi; }
        }
        float p = expf(logit - v1);
        float ssum = p;
        #pragma unroll
        for (int off = 32; off; off >>= 1) ssum += __shfl_xor(ssum, off);

        float v2 = (lane == i1) ? -3.402823466e38f : logit;
        int i2 = lane;
        #pragma unroll
        for (int off = 32; off; off >>= 1) {
            float ov = __shfl_xor(v2, off);
            int   oi = __shfl_xor(i2, off);
            if (ov > v2 || (ov == v2 && oi < i2)) { v2 = ov; i2 = oi; }
        }

        impAcc += p / ssum;                    // this lane's expert prob
        cntAcc += (i1 == lane) ? 1.f : 0.f;    // top-1 histogram

        if (lane == 0) {
            int srow = row0 + r;
            outIdx[srow * 2 + 0] = (float)i1;
            outIdx[srow * 2 + 1] = (float)i2;
            outVal[srow * 2 + 0] = 1.f / ssum;             // exp(v1-v1)/sum
            outVal[srow * 2 + 1] = expf(v2 - v1) / ssum;
        }
    }

    // ---- per-block reduce of importance / count partials ----
    __syncthreads();
    float* redImp = Wl;         // reuse LDS: [4][64]
    float* redCnt = Wl + 256;   // [4][64]
    redImp[wid * 64 + lane] = impAcc;
    redCnt[wid * 64 + lane] = cntAcc;
    __syncthreads();
    if (tid < 64) {
        float si = 0.f, sc = 0.f;
        #pragma unroll
        for (int g = 0; g < NWAVE; ++g) { si += redImp[g * 64 + tid]; sc += redCnt[g * 64 + tid]; }
        ws[(size_t)blk * 64 + tid] = si;
        ws[(size_t)NBLK * 64 + (size_t)blk * 64 + tid] = sc;
    }
}

__global__ void gate_reduce(const float* __restrict__ ws, float* __restrict__ out)
{
    __shared__ float li[4 * 64], lc[4 * 64], lp[64];
    const int t = threadIdx.x;
    const int e = t & 63, g = t >> 6;
    float si = 0.f, sc = 0.f;
    const int per = NBLK / 4;
    for (int bb = g * per; bb < (g + 1) * per; ++bb) {
        si += ws[(size_t)bb * 64 + e];
        sc += ws[(size_t)NBLK * 64 + (size_t)bb * 64 + e];
    }
    li[g * 64 + e] = si;
    lc[g * 64 + e] = sc;
    __syncthreads();
    if (t < 64) {
        float ti = 0.f, tc = 0.f;
        #pragma unroll
        for (int gg = 0; gg < 4; ++gg) { ti += li[gg * 64 + t]; tc += lc[gg * 64 + t]; }
        lp[t] = ti * tc;
    }
    __syncthreads();
    if (t == 0) {
        float s = 0.f;
        for (int i = 0; i < NE; ++i) s += lp[i];
        // aux = E * sum_e (imp_e/S) * (cnt_e/S)
        out[(size_t)SROWS * 4] = s * ((float)NE / ((float)SROWS * (float)SROWS));
    }
}

extern "C" void kernel_launch(void* const* d_in, const int* in_sizes, int n_in,
                              void* d_out, int out_size, void* d_ws, size_t ws_size,
                              hipStream_t stream)
{
    const float* x = (const float*)d_in[0];
    const float* W = (const float*)d_in[1];
    const float* b = (const float*)d_in[2];
    float* out = (float*)d_out;
    float* ws  = (float*)d_ws;

    gate_main<<<NBLK, 256, 0, stream>>>(x, W, b, out, ws);
    gate_reduce<<<1, 256, 0, stream>>>(ws, out);
}

// Round 2
// 521.447 us; speedup vs baseline: 1.0309x; 1.0309x over previous
//
#include <hip/hip_runtime.h>
#include <hip/hip_bf16.h>

#define SROWS 16384
#define DIMK  4096
#define NE    64
#define BRK   64                 // rows per block (lane = row)
#define NBLK  (SROWS/BRK)        // 256 blocks
#define DC    64                 // D-chunk staged in LDS
#define PITCH 68                 // padded row pitch (16B-aligned)
#define NCH   (DIMK/DC)          // 64 chunks
#define NW    16                 // waves per block

__global__ __launch_bounds__(1024, 1) void gate_main(
    const float* __restrict__ x, const float* __restrict__ W,
    const float* __restrict__ b, float* __restrict__ out, float* __restrict__ ws)
{
    __shared__ float smem[2 * BRK * PITCH];   // 8704 floats = 34816 B (reused by epilogue)
    const int tid  = threadIdx.x;
    const int lane = tid & 63;
    const int wid  = __builtin_amdgcn_readfirstlane(tid >> 6);  // 0..15
    const int eh   = wid & 1;      // expert half: experts eh*32 .. +31
    const int dq   = wid >> 1;     // d-octant within each chunk: 8 floats
    const int blk  = blockIdx.x;
    const int row0 = blk * BRK;

    // staging role: thread loads one float4 of the x tile per chunk
    const int srow = tid >> 4;     // 0..63
    const int sc4  = tid & 15;     // 0..15
    const float* xg = x + (size_t)(row0 + srow) * DIMK + sc4 * 4;

    // prologue: stage chunk 0 into buf0
    {
        float4 v = *reinterpret_cast<const float4*>(xg);
        *reinterpret_cast<float4*>(&smem[srow * PITCH + sc4 * 4]) = v;
    }
    __syncthreads();

    float acc[32];
    #pragma unroll
    for (int i = 0; i < 32; ++i) acc[i] = 0.f;

    const int d0 = dq * 8;

    #pragma unroll 1
    for (int ch = 0; ch < NCH; ++ch) {
        const float* cb = &smem[(ch & 1) * (BRK * PITCH)];
        float4 pf;
        const bool hasNext = (ch + 1) < NCH;
        if (hasNext) pf = *reinterpret_cast<const float4*>(xg + (size_t)(ch + 1) * DC);

        // this lane's row slice: 8 d-values from LDS
        const float* xp = cb + lane * PITCH + d0;
        const float4 xv0 = *reinterpret_cast<const float4*>(xp);
        const float4 xv1 = *reinterpret_cast<const float4*>(xp + 4);

        // W is wave-uniform -> scalar loads feeding v_fmac s-operand
        const float* wp = W + (size_t)(eh * 32) * DIMK + ch * DC + d0;
        #pragma unroll
        for (int ep = 0; ep < 16; ++ep) {
            const float* wA = wp + (size_t)(2 * ep) * DIMK;
            const float* wB = wA + DIMK;
            const float4 a0 = *reinterpret_cast<const float4*>(wA);
            const float4 a1 = *reinterpret_cast<const float4*>(wA + 4);
            const float4 c0 = *reinterpret_cast<const float4*>(wB);
            const float4 c1 = *reinterpret_cast<const float4*>(wB + 4);
            float aA = acc[2 * ep];
            float aB = acc[2 * ep + 1];
            aA = fmaf(a0.x, xv0.x, aA); aA = fmaf(a0.y, xv0.y, aA);
            aA = fmaf(a0.z, xv0.z, aA); aA = fmaf(a0.w, xv0.w, aA);
            aA = fmaf(a1.x, xv1.x, aA); aA = fmaf(a1.y, xv1.y, aA);
            aA = fmaf(a1.z, xv1.z, aA); aA = fmaf(a1.w, xv1.w, aA);
            aB = fmaf(c0.x, xv0.x, aB); aB = fmaf(c0.y, xv0.y, aB);
            aB = fmaf(c0.z, xv0.z, aB); aB = fmaf(c0.w, xv0.w, aB);
            aB = fmaf(c1.x, xv1.x, aB); aB = fmaf(c1.y, xv1.y, aB);
            aB = fmaf(c1.z, xv1.z, aB); aB = fmaf(c1.w, xv1.w, aB);
            acc[2 * ep]     = aA;
            acc[2 * ep + 1] = aB;
        }

        if (hasNext) {
            float* nb = &smem[((ch + 1) & 1) * (BRK * PITCH)];
            *reinterpret_cast<float4*>(&nb[srow * PITCH + sc4 * 4]) = pf;
        }
        __syncthreads();
    }

    // ---- reduce partial logits across the 8 d-octants via LDS ----
    // L2 layout: smem[e * 65 + row], 64x65 floats
    for (int q = 0; q < 8; ++q) {
        if (dq == q) {
            #pragma unroll
            for (int el = 0; el < 32; ++el) {
                const int e = eh * 32 + el;
                float* p = &smem[e * 65 + lane];
                if (q == 0) *p = acc[el];
                else        *p += acc[el];
            }
        }
        __syncthreads();
    }

    // ---- epilogue: softmax + top-2 per row (lane = expert), 4 rows/wave ----
    float impAcc = 0.f, cntAcc = 0.f;
    const float blane = b[lane];
    float* outIdx = out;
    float* outVal = out + (size_t)SROWS * 2;

    #pragma unroll 1
    for (int rr = 0; rr < 4; ++rr) {
        const int r = wid * 4 + rr;
        const float logit = smem[lane * 65 + r] + blane;

        // argmax with lowest-index tie-break (matches jax.lax.top_k)
        float v1 = logit; int i1 = lane;
        #pragma unroll
        for (int off = 32; off; off >>= 1) {
            float ov = __shfl_xor(v1, off);
            int   oi = __shfl_xor(i1, off);
            if (ov > v1 || (ov == v1 && oi < i1)) { v1 = ov; i1 = oi; }
        }
        float p = expf(logit - v1);
        float ssum = p;
        #pragma unroll
        for (int off = 32; off; off >>= 1) ssum += __shfl_xor(ssum, off);

        float v2 = (lane == i1) ? -3.402823466e38f : logit;
        int i2 = lane;
        #pragma unroll
        for (int off = 32; off; off >>= 1) {
            float ov = __shfl_xor(v2, off);
            int   oi = __shfl_xor(i2, off);
            if (ov > v2 || (ov == v2 && oi < i2)) { v2 = ov; i2 = oi; }
        }

        impAcc += p / ssum;
        cntAcc += (i1 == lane) ? 1.f : 0.f;

        if (lane == 0) {
            const int sr = row0 + r;
            outIdx[sr * 2 + 0] = (float)i1;
            outIdx[sr * 2 + 1] = (float)i2;
            outVal[sr * 2 + 0] = 1.f / ssum;
            outVal[sr * 2 + 1] = expf(v2 - v1) / ssum;
        }
    }

    // ---- per-block reduce of importance / count partials ----
    __syncthreads();
    smem[wid * 64 + lane]        = impAcc;
    smem[1024 + wid * 64 + lane] = cntAcc;
    __syncthreads();
    if (tid < 64) {
        float si = 0.f, sc = 0.f;
        #pragma unroll
        for (int g = 0; g < NW; ++g) {
            si += smem[g * 64 + tid];
            sc += smem[1024 + g * 64 + tid];
        }
        ws[(size_t)blk * 64 + tid] = si;
        ws[(size_t)NBLK * 64 + (size_t)blk * 64 + tid] = sc;
    }
}

__global__ void gate_reduce(const float* __restrict__ ws, float* __restrict__ out)
{
    __shared__ float li[4 * 64], lc[4 * 64], lp[64];
    const int t = threadIdx.x;
    const int e = t & 63, g = t >> 6;
    float si = 0.f, sc = 0.f;
    const int per = NBLK / 4;     // 64
    for (int bb = g * per; bb < (g + 1) * per; ++bb) {
        si += ws[(size_t)bb * 64 + e];
        sc += ws[(size_t)NBLK * 64 + (size_t)bb * 64 + e];
    }
    li[g * 64 + e] = si;
    lc[g * 64 + e] = sc;
    __syncthreads();
    if (t < 64) {
        float ti = 0.f, tc = 0.f;
        #pragma unroll
        for (int gg = 0; gg < 4; ++gg) { ti += li[gg * 64 + t]; tc += lc[gg * 64 + t]; }
        lp[t] = ti * tc;
    }
    __syncthreads();
    if (t == 0) {
        float s = 0.f;
        for (int i = 0; i < NE; ++i) s += lp[i];
        out[(size_t)SROWS * 4] = s * ((float)NE / ((float)SROWS * (float)SROWS));
    }
}

extern "C" void kernel_launch(void* const* d_in, const int* in_sizes, int n_in,
                              void* d_out, int out_size, void* d_ws, size_t ws_size,
                              hipStream_t stream)
{
    const float* x = (const float*)d_in[0];
    const float* W = (const float*)d_in[1];
    const float* b = (const float*)d_in[2];
    float* out = (float*)d_out;
    float* ws  = (float*)d_ws;

    gate_main<<<NBLK, 1024, 0, stream>>>(x, W, b, out, ws);
    gate_reduce<<<1, 256, 0, stream>>>(ws, out);
}